// Round 1
// baseline (4159.873 us; speedup 1.0000x reference)
//
#include <hip/hip_runtime.h>
#include <stdint.h>

#define H 128
#define FN 133
#define FE 14
#define NG 1024

// ---------------- mask dtype sniff ----------------
// flag: 0 = int32 {0,1}, 1 = packed bytes, 2 = float32 {0.0,1.0}
__global__ void k_sniff(const unsigned int* __restrict__ w, int nwords, int* __restrict__ flag) {
    __shared__ int sawFloat, sawBig;
    if (threadIdx.x == 0) { sawFloat = 0; sawBig = 0; }
    __syncthreads();
    int f = 0, bg = 0;
    for (int i = threadIdx.x; i < nwords; i += blockDim.x) {
        unsigned int v = w[i];
        if (v == 0u || v == 1u) continue;
        if (v == 0x3F800000u) f = 1; else bg = 1;
    }
    if (f) atomicOr(&sawFloat, 1);
    if (bg) atomicOr(&sawBig, 1);
    __syncthreads();
    if (threadIdx.x == 0) *flag = sawBig ? 1 : (sawFloat ? 2 : 0);
}

// ---------------- node encoder: h = relu(x[map?] @ w + b) ----------------
template<bool GATHER>
__global__ __launch_bounds__(256)
void k_node_enc(const float* __restrict__ x, const int* __restrict__ map,
                int nrows, const float* __restrict__ w, const float* __restrict__ b,
                float* __restrict__ h) {
    __shared__ float w_lds[FN * 64];
    __shared__ float x_lds[4][FN];
    __shared__ float b_lds[64];
    const int cbase = blockIdx.y * 64;
    for (int i = threadIdx.x; i < FN * 64; i += 256)
        w_lds[i] = w[(i >> 6) * H + cbase + (i & 63)];
    if (threadIdx.x < 64) b_lds[threadIdx.x] = b[cbase + threadIdx.x];
    __syncthreads();
    const int grp = threadIdx.x >> 6, c = threadIdx.x & 63;
    for (int base = blockIdx.x * 4; base < nrows; base += gridDim.x * 4) {
        for (int i = threadIdx.x; i < 4 * FN; i += 256) {
            int rr = base + i / FN;
            float v = 0.f;
            if (rr < nrows) {
                int sr = GATHER ? map[rr] : rr;
                v = x[(size_t)sr * FN + (i % FN)];
            }
            x_lds[i / FN][i % FN] = v;
        }
        __syncthreads();
        int row = base + grp;
        if (row < nrows) {
            float acc = b_lds[c];
            #pragma unroll 7
            for (int k = 0; k < FN; ++k) acc += x_lds[grp][k] * w_lds[(k << 6) + c];
            h[(size_t)row * H + cbase + c] = fmaxf(acc, 0.f);
        }
        __syncthreads();
    }
}

// ---------------- fused edge-encode + message + scatter-add ----------------
// agg[dst] += ew * (h[src] + relu(edge_attr @ w_edge + b_edge))
template<int MODE>   // 0 = full graph, 1 = ctx subgraph (edge gather + mask)
__global__ __launch_bounds__(256)
void k_msg(const int* __restrict__ src, const int* __restrict__ dst,
           const float* __restrict__ edge_weight,
           const int* __restrict__ emap, const void* __restrict__ mask,
           const int* __restrict__ mmode_p,
           const float* __restrict__ edge_attr,
           const float* __restrict__ w_edge, const float* __restrict__ b_edge,
           const float* __restrict__ h, float* __restrict__ agg,
           int nedges) {
    __shared__ float we_lds[FE * H];
    __shared__ float be_lds[H];
    for (int i = threadIdx.x; i < FE * H; i += 256) we_lds[i] = w_edge[i];
    if (threadIdx.x < H) be_lds[threadIdx.x] = b_edge[threadIdx.x];
    __syncthreads();
    int mm = 0;
    if (MODE) mm = *mmode_p;
    const int grp = threadIdx.x >> 7, c = threadIdx.x & 127;
    for (long e = (long)blockIdx.x * 2 + grp; e < nedges; e += (long)gridDim.x * 2) {
        int eo = MODE ? emap[e] : (int)e;
        float w = edge_weight[eo];
        if (MODE) {
            float m;
            if (mm == 1)      m = ((const unsigned char*)mask)[e] ? 1.f : 0.f;
            else if (mm == 2) m = ((const float*)mask)[e];
            else              m = ((const int*)mask)[e] ? 1.f : 0.f;
            w *= m;
        }
        if (w != 0.f) {
            const float* ea = edge_attr + (size_t)eo * FE;
            float eh = be_lds[c];
            #pragma unroll
            for (int k = 0; k < FE; ++k) eh += ea[k] * we_lds[k * H + c];
            eh = fmaxf(eh, 0.f);
            int s = src[e], d = dst[e];
            float msg = w * (h[(size_t)s * H + c] + eh);
            atomicAdd(&agg[(size_t)d * H + c], msg);
        }
    }
}

// ---------------- h = relu(h + agg @ w_mp + b_mp), in place ----------------
__global__ __launch_bounds__(256)
void k_update(float* __restrict__ h, const float* __restrict__ agg,
              const float* __restrict__ w, const float* __restrict__ b, int nrows) {
    __shared__ float w_lds[H * 64];
    __shared__ float a_lds[4][H];
    __shared__ float b_lds[64];
    const int cbase = blockIdx.y * 64;
    for (int i = threadIdx.x; i < H * 64; i += 256)
        w_lds[i] = w[(i >> 6) * H + cbase + (i & 63)];
    if (threadIdx.x < 64) b_lds[threadIdx.x] = b[cbase + threadIdx.x];
    __syncthreads();
    const int grp = threadIdx.x >> 6, c = threadIdx.x & 63;
    for (int base = blockIdx.x * 4; base < nrows; base += gridDim.x * 4) {
        for (int i = threadIdx.x; i < 4 * H; i += 256) {
            int r = base + (i >> 7);
            a_lds[i >> 7][i & 127] = (r < nrows) ? agg[(size_t)r * H + (i & 127)] : 0.f;
        }
        __syncthreads();
        int row = base + grp;
        if (row < nrows) {
            float acc = b_lds[c];
            #pragma unroll 8
            for (int k = 0; k < H; ++k) acc += a_lds[grp][k] * w_lds[(k << 6) + c];
            size_t idx = (size_t)row * H + cbase + c;
            h[idx] = fmaxf(h[idx] + acc, 0.f);
        }
        __syncthreads();
    }
}

// ---------------- fused output matmul + weighted scale + segment pool ----------------
// per row r: val = (h[hrow] @ w_out + b_out) * node_weight[oid];  gsum[batch[oid]] += val
template<bool TGT>   // TGT: hrow = rowmap[r] (gather from full h); else hrow = r (ctx)
__global__ __launch_bounds__(256)
void k_out_pool(const float* __restrict__ h, const int* __restrict__ rowmap,
                const int* __restrict__ batch, const float* __restrict__ nodew,
                const float* __restrict__ w, const float* __restrict__ b,
                float* __restrict__ gsum, int* __restrict__ gcnt, int nrows) {
    __shared__ float w_lds[H * 64];
    __shared__ float r_lds[4][H];
    __shared__ float b_lds[64];
    const int ct = blockIdx.y, cbase = ct * 64;
    for (int i = threadIdx.x; i < H * 64; i += 256)
        w_lds[i] = w[(i >> 6) * H + cbase + (i & 63)];
    if (threadIdx.x < 64) b_lds[threadIdx.x] = b[cbase + threadIdx.x];
    __syncthreads();
    const int grp = threadIdx.x >> 6, c = threadIdx.x & 63;
    for (int base = blockIdx.x * 4; base < nrows; base += gridDim.x * 4) {
        for (int i = threadIdx.x; i < 4 * H; i += 256) {
            int r = base + (i >> 7);
            float v = 0.f;
            if (r < nrows) {
                int hr = TGT ? rowmap[r] : r;
                v = h[(size_t)hr * H + (i & 127)];
            }
            r_lds[i >> 7][i & 127] = v;
        }
        __syncthreads();
        int row = base + grp;
        if (row < nrows) {
            int oid = rowmap[row];
            float nw = nodew[oid];
            int g = batch[oid];
            float acc = b_lds[c];
            #pragma unroll 8
            for (int k = 0; k < H; ++k) acc += r_lds[grp][k] * w_lds[(k << 6) + c];
            atomicAdd(&gsum[(size_t)g * H + cbase + c], acc * nw);
            if (ct == 0 && c == 0) atomicAdd(&gcnt[g], 1);
        }
        __syncthreads();
    }
}

// ---------------- finalize: divide sums by counts ----------------
__global__ void k_finalize(const float* __restrict__ sc, const int* __restrict__ cc,
                           const float* __restrict__ st, const int* __restrict__ ct,
                           float* __restrict__ out) {
    int i = blockIdx.x * 256 + threadIdx.x;
    if (i < NG * H) {
        int g = i >> 7;
        out[i]          = sc[i] / fmaxf((float)cc[g], 1.f);
        out[NG * H + i] = st[i] / fmaxf((float)ct[g], 1.f);
    }
}

extern "C" void kernel_launch(void* const* d_in, const int* in_sizes, int n_in,
                              void* d_out, int out_size, void* d_ws, size_t ws_size,
                              hipStream_t stream) {
    (void)n_in; (void)out_size;
    const float* x           = (const float*)d_in[0];
    const float* node_weight = (const float*)d_in[1];
    const int*   edge_index  = (const int*)d_in[2];
    const float* edge_attr   = (const float*)d_in[3];
    const float* edge_weight = (const float*)d_in[4];
    const int*   batch       = (const int*)d_in[5];
    const int*   cnm         = (const int*)d_in[6];
    const int*   tnm         = (const int*)d_in[7];
    const int*   csub        = (const int*)d_in[8];
    const int*   sem         = (const int*)d_in[9];
    const void*  cmask       = d_in[10];

    const float* ctx_w_node = (const float*)d_in[11];
    const float* ctx_b_node = (const float*)d_in[12];
    const float* ctx_w_edge = (const float*)d_in[13];
    const float* ctx_b_edge = (const float*)d_in[14];
    const float* ctx_w_mp   = (const float*)d_in[15];
    const float* ctx_b_mp   = (const float*)d_in[16];
    const float* ctx_w_out  = (const float*)d_in[17];
    const float* ctx_b_out  = (const float*)d_in[18];
    const float* tgt_w_node = (const float*)d_in[19];
    const float* tgt_b_node = (const float*)d_in[20];
    const float* tgt_w_edge = (const float*)d_in[21];
    const float* tgt_b_edge = (const float*)d_in[22];
    const float* tgt_w_mp   = (const float*)d_in[23];
    const float* tgt_b_mp   = (const float*)d_in[24];
    const float* tgt_w_out  = (const float*)d_in[25];
    const float* tgt_b_out  = (const float*)d_in[26];

    const int N  = in_sizes[1];
    const int E  = in_sizes[4];
    const int NC = in_sizes[6];
    const int NT = in_sizes[7];
    const int ES = in_sizes[9];

    float* out = (float*)d_out;

    // workspace layout
    char* ws = (char*)d_ws;
    float* h_full = (float*)ws;  ws += (size_t)N  * H * sizeof(float);
    float* h_ctx  = (float*)ws;  ws += (size_t)NC * H * sizeof(float);
    float* agg    = (float*)ws;  ws += (size_t)N  * H * sizeof(float);
    float* sum_ctx = (float*)ws; ws += (size_t)NG * H * sizeof(float);
    float* sum_tgt = (float*)ws; ws += (size_t)NG * H * sizeof(float);
    int*   cnt_ctx = (int*)ws;   ws += (size_t)NG * sizeof(int);
    int*   cnt_tgt = (int*)ws;   ws += (size_t)NG * sizeof(int);
    int*   flag    = (int*)ws;   ws += sizeof(int);
    (void)ws_size;

    // zero pooled sums/counts/flag (contiguous region)
    size_t sums_bytes = (size_t)(2 * NG * H) * sizeof(float) + (size_t)(2 * NG) * sizeof(int) + sizeof(int);
    hipMemsetAsync(sum_ctx, 0, sums_bytes, stream);

    // sniff mask dtype
    int nwords = ES / 4; if (nwords > 8192) nwords = 8192;
    k_sniff<<<1, 256, 0, stream>>>((const unsigned int*)cmask, nwords, flag);

    const int GEMM_GX = 2048;
    const int MSG_GX  = 8192;

    // ---------- FULL graph pass (tgt params) ----------
    k_node_enc<false><<<dim3(GEMM_GX, 2), 256, 0, stream>>>(x, nullptr, N, tgt_w_node, tgt_b_node, h_full);
    for (int t = 0; t < 3; ++t) {
        hipMemsetAsync(agg, 0, (size_t)N * H * sizeof(float), stream);
        k_msg<0><<<MSG_GX, 256, 0, stream>>>(edge_index, edge_index + E, edge_weight,
                                             nullptr, nullptr, nullptr,
                                             edge_attr, tgt_w_edge, tgt_b_edge,
                                             h_full, agg, E);
        k_update<<<dim3(GEMM_GX, 2), 256, 0, stream>>>(h_full, agg, tgt_w_mp + t * H * H, tgt_b_mp + t * H, N);
    }
    k_out_pool<true><<<dim3(1024, 2), 256, 0, stream>>>(h_full, tnm, batch, node_weight,
                                                        tgt_w_out, tgt_b_out, sum_tgt, cnt_tgt, NT);

    // ---------- CTX subgraph pass (ctx params) ----------
    k_node_enc<true><<<dim3(GEMM_GX, 2), 256, 0, stream>>>(x, cnm, NC, ctx_w_node, ctx_b_node, h_ctx);
    for (int t = 0; t < 3; ++t) {
        hipMemsetAsync(agg, 0, (size_t)NC * H * sizeof(float), stream);
        k_msg<1><<<MSG_GX, 256, 0, stream>>>(csub, csub + ES, edge_weight,
                                             sem, cmask, flag,
                                             edge_attr, ctx_w_edge, ctx_b_edge,
                                             h_ctx, agg, ES);
        k_update<<<dim3(GEMM_GX, 2), 256, 0, stream>>>(h_ctx, agg, ctx_w_mp + t * H * H, ctx_b_mp + t * H, NC);
    }
    k_out_pool<false><<<dim3(1024, 2), 256, 0, stream>>>(h_ctx, cnm, batch, node_weight,
                                                         ctx_w_out, ctx_b_out, sum_ctx, cnt_ctx, NC);

    k_finalize<<<512, 256, 0, stream>>>(sum_ctx, cnt_ctx, sum_tgt, cnt_tgt, out);
}

// Round 2
// 2953.366 us; speedup vs baseline: 1.4085x; 1.4085x over previous
//
#include <hip/hip_runtime.h>
#include <stdint.h>

#define H 128
#define FN 133
#define FE 14
#define NG 1024

// ---------------- mask dtype sniff ----------------
// flag: 0 = int32 {0,1}, 1 = packed bytes, 2 = float32 {0.0,1.0}
__global__ void k_sniff(const unsigned int* __restrict__ w, int nwords, int* __restrict__ flag) {
    __shared__ int sawFloat, sawBig;
    if (threadIdx.x == 0) { sawFloat = 0; sawBig = 0; }
    __syncthreads();
    int f = 0, bg = 0;
    for (int i = threadIdx.x; i < nwords; i += blockDim.x) {
        unsigned int v = w[i];
        if (v == 0u || v == 1u) continue;
        if (v == 0x3F800000u) f = 1; else bg = 1;
    }
    if (f) atomicOr(&sawFloat, 1);
    if (bg) atomicOr(&sawBig, 1);
    __syncthreads();
    if (threadIdx.x == 0) *flag = sawBig ? 1 : (sawFloat ? 2 : 0);
}

// =====================================================================
// Register-tiled fp32 GEMM family: block = 256 threads -> 64 rows x 64 cols,
// thread = 4x4 micro-tile. A staged transposed in LDS (a_lds[k][row]) so both
// fragments are ds_read_b128. 2 LDS instr per 16 FMA -> VALU-bound.
// grid = (ceil(nrows/64), 2)  [blockIdx.y = 64-col slice]
// =====================================================================

// ---------------- node encoder: h = relu(x[map?] @ w + b), K = 133 ----------------
template<bool GATHER>
__global__ __launch_bounds__(256)
void k_gemm_enc(const float* __restrict__ x, const int* __restrict__ map, int nrows,
                const float* __restrict__ w, const float* __restrict__ bias,
                float* __restrict__ hout) {
    __shared__ float w_lds[FN][64];
    __shared__ float a_lds[67][68];
    const int cbase = blockIdx.y * 64;
    for (int i = threadIdx.x; i < FN * 64; i += 256)
        w_lds[i >> 6][i & 63] = w[(i >> 6) * H + cbase + (i & 63)];
    const int tx = threadIdx.x & 15, ty = threadIdx.x >> 4;
    const int rbase = blockIdx.x * 64;
    float acc[4][4] = {};
    #pragma unroll
    for (int kc = 0; kc < 2; ++kc) {
        const int k0 = kc * 67;
        const int klen = kc ? 66 : 67;
        __syncthreads();
        for (int i = threadIdx.x; i < 64 * 67; i += 256) {
            int r = i / 67, kk = i % 67;
            int row = rbase + r;
            float v = 0.f;
            if (kk < klen && row < nrows) {
                int sr = GATHER ? map[row] : row;
                v = x[(size_t)sr * FN + k0 + kk];
            }
            a_lds[kk][r] = v;
        }
        __syncthreads();
        #pragma unroll 4
        for (int k = 0; k < klen; ++k) {
            float4 av = reinterpret_cast<const float4*>(&a_lds[k][0])[ty];
            float4 wv = reinterpret_cast<const float4*>(&w_lds[k0 + k][0])[tx];
            float aa[4] = {av.x, av.y, av.z, av.w};
            float ww[4] = {wv.x, wv.y, wv.z, wv.w};
            #pragma unroll
            for (int i2 = 0; i2 < 4; ++i2)
                #pragma unroll
                for (int j = 0; j < 4; ++j)
                    acc[i2][j] += aa[i2] * ww[j];
        }
    }
    float4 bv = reinterpret_cast<const float4*>(bias + cbase)[tx];
    float bb[4] = {bv.x, bv.y, bv.z, bv.w};
    #pragma unroll
    for (int i2 = 0; i2 < 4; ++i2) {
        int row = rbase + ty * 4 + i2;
        if (row < nrows) {
            float4 o;
            o.x = fmaxf(acc[i2][0] + bb[0], 0.f);
            o.y = fmaxf(acc[i2][1] + bb[1], 0.f);
            o.z = fmaxf(acc[i2][2] + bb[2], 0.f);
            o.w = fmaxf(acc[i2][3] + bb[3], 0.f);
            *reinterpret_cast<float4*>(hout + (size_t)row * H + cbase + tx * 4) = o;
        }
    }
}

// ---------------- h = relu(h + agg @ w_mp + b_mp), K = 128, in place ----------------
__global__ __launch_bounds__(256)
void k_gemm_update(const float* __restrict__ agg, int nrows,
                   const float* __restrict__ w, const float* __restrict__ bias,
                   float* __restrict__ h) {
    __shared__ float w_lds[H][64];
    __shared__ float a_lds[64][68];
    const int cbase = blockIdx.y * 64;
    for (int i = threadIdx.x; i < H * 64; i += 256)
        w_lds[i >> 6][i & 63] = w[(i >> 6) * H + cbase + (i & 63)];
    const int tx = threadIdx.x & 15, ty = threadIdx.x >> 4;
    const int rbase = blockIdx.x * 64;
    const bool full = (rbase + 64 <= nrows);
    float acc[4][4] = {};
    #pragma unroll
    for (int kc = 0; kc < 2; ++kc) {
        const int k0 = kc * 64;
        __syncthreads();
        for (int i = threadIdx.x; i < 1024; i += 256) {
            int r = i >> 4, f = i & 15;
            int row = rbase + r;
            float4 v = make_float4(0.f, 0.f, 0.f, 0.f);
            if (full || row < nrows)
                v = reinterpret_cast<const float4*>(agg + (size_t)row * H + k0)[f];
            a_lds[f * 4 + 0][r] = v.x;
            a_lds[f * 4 + 1][r] = v.y;
            a_lds[f * 4 + 2][r] = v.z;
            a_lds[f * 4 + 3][r] = v.w;
        }
        __syncthreads();
        #pragma unroll 8
        for (int k = 0; k < 64; ++k) {
            float4 av = reinterpret_cast<const float4*>(&a_lds[k][0])[ty];
            float4 wv = reinterpret_cast<const float4*>(&w_lds[k0 + k][0])[tx];
            float aa[4] = {av.x, av.y, av.z, av.w};
            float ww[4] = {wv.x, wv.y, wv.z, wv.w};
            #pragma unroll
            for (int i2 = 0; i2 < 4; ++i2)
                #pragma unroll
                for (int j = 0; j < 4; ++j)
                    acc[i2][j] += aa[i2] * ww[j];
        }
    }
    float4 bv = reinterpret_cast<const float4*>(bias + cbase)[tx];
    float bb[4] = {bv.x, bv.y, bv.z, bv.w};
    #pragma unroll
    for (int i2 = 0; i2 < 4; ++i2) {
        int row = rbase + ty * 4 + i2;
        if (row < nrows) {
            size_t base = (size_t)row * H + cbase + tx * 4;
            float4 hv = *reinterpret_cast<const float4*>(h + base);
            float4 o;
            o.x = fmaxf(hv.x + acc[i2][0] + bb[0], 0.f);
            o.y = fmaxf(hv.y + acc[i2][1] + bb[1], 0.f);
            o.z = fmaxf(hv.z + acc[i2][2] + bb[2], 0.f);
            o.w = fmaxf(hv.w + acc[i2][3] + bb[3], 0.f);
            *reinterpret_cast<float4*>(h + base) = o;
        }
    }
}

// ------- out = (h[row?] @ w_out + b_out) * nw; gsum[batch] += out; K = 128 -------
template<bool GATHER>
__global__ __launch_bounds__(256)
void k_gemm_pool(const float* __restrict__ h, const int* __restrict__ rowmap,
                 const int* __restrict__ batch, const float* __restrict__ nodew,
                 const float* __restrict__ w, const float* __restrict__ bias,
                 float* __restrict__ gsum, int* __restrict__ gcnt, int nrows) {
    __shared__ float w_lds[H][64];
    __shared__ float a_lds[64][68];
    const int cbase = blockIdx.y * 64;
    for (int i = threadIdx.x; i < H * 64; i += 256)
        w_lds[i >> 6][i & 63] = w[(i >> 6) * H + cbase + (i & 63)];
    const int tx = threadIdx.x & 15, ty = threadIdx.x >> 4;
    const int rbase = blockIdx.x * 64;
    float acc[4][4] = {};
    #pragma unroll
    for (int kc = 0; kc < 2; ++kc) {
        const int k0 = kc * 64;
        __syncthreads();
        for (int i = threadIdx.x; i < 1024; i += 256) {
            int r = i >> 4, f = i & 15;
            int row = rbase + r;
            float4 v = make_float4(0.f, 0.f, 0.f, 0.f);
            if (row < nrows) {
                int hr = GATHER ? rowmap[row] : row;
                v = reinterpret_cast<const float4*>(h + (size_t)hr * H + k0)[f];
            }
            a_lds[f * 4 + 0][r] = v.x;
            a_lds[f * 4 + 1][r] = v.y;
            a_lds[f * 4 + 2][r] = v.z;
            a_lds[f * 4 + 3][r] = v.w;
        }
        __syncthreads();
        #pragma unroll 8
        for (int k = 0; k < 64; ++k) {
            float4 av = reinterpret_cast<const float4*>(&a_lds[k][0])[ty];
            float4 wv = reinterpret_cast<const float4*>(&w_lds[k0 + k][0])[tx];
            float aa[4] = {av.x, av.y, av.z, av.w};
            float ww[4] = {wv.x, wv.y, wv.z, wv.w};
            #pragma unroll
            for (int i2 = 0; i2 < 4; ++i2)
                #pragma unroll
                for (int j = 0; j < 4; ++j)
                    acc[i2][j] += aa[i2] * ww[j];
        }
    }
    float4 bv = reinterpret_cast<const float4*>(bias + cbase)[tx];
    float bb[4] = {bv.x, bv.y, bv.z, bv.w};
    #pragma unroll
    for (int i2 = 0; i2 < 4; ++i2) {
        int row = rbase + ty * 4 + i2;
        if (row < nrows) {
            int oid = rowmap[row];
            float nw = nodew[oid];
            int g = batch[oid];
            float* gp = gsum + (size_t)g * H + cbase + tx * 4;
            atomicAdd(gp + 0, (acc[i2][0] + bb[0]) * nw);
            atomicAdd(gp + 1, (acc[i2][1] + bb[1]) * nw);
            atomicAdd(gp + 2, (acc[i2][2] + bb[2]) * nw);
            atomicAdd(gp + 3, (acc[i2][3] + bb[3]) * nw);
            if (blockIdx.y == 0 && tx == 0) atomicAdd(&gcnt[g], 1);
        }
    }
}

// ---------------- fused edge-encode + message + scatter-add ----------------
// agg[dst] += ew * (h[src] + relu(edge_attr @ w_edge + b_edge))
template<int MODE>   // 0 = full graph, 1 = ctx subgraph (edge gather + mask)
__global__ __launch_bounds__(256)
void k_msg(const int* __restrict__ src, const int* __restrict__ dst,
           const float* __restrict__ edge_weight,
           const int* __restrict__ emap, const void* __restrict__ mask,
           const int* __restrict__ mmode_p,
           const float* __restrict__ edge_attr,
           const float* __restrict__ w_edge, const float* __restrict__ b_edge,
           const float* __restrict__ h, float* __restrict__ agg,
           int nedges) {
    __shared__ float we_lds[FE * H];
    __shared__ float be_lds[H];
    for (int i = threadIdx.x; i < FE * H; i += 256) we_lds[i] = w_edge[i];
    if (threadIdx.x < H) be_lds[threadIdx.x] = b_edge[threadIdx.x];
    __syncthreads();
    int mm = 0;
    if (MODE) mm = *mmode_p;
    const int grp = threadIdx.x >> 7, c = threadIdx.x & 127;
    for (long e = (long)blockIdx.x * 2 + grp; e < nedges; e += (long)gridDim.x * 2) {
        int eo = MODE ? emap[e] : (int)e;
        float w = edge_weight[eo];
        if (MODE) {
            float m;
            if (mm == 1)      m = ((const unsigned char*)mask)[e] ? 1.f : 0.f;
            else if (mm == 2) m = ((const float*)mask)[e];
            else              m = ((const int*)mask)[e] ? 1.f : 0.f;
            w *= m;
        }
        if (w != 0.f) {
            const float* ea = edge_attr + (size_t)eo * FE;
            float eh = be_lds[c];
            #pragma unroll
            for (int k = 0; k < FE; ++k) eh += ea[k] * we_lds[k * H + c];
            eh = fmaxf(eh, 0.f);
            int s = src[e], d = dst[e];
            float msg = w * (h[(size_t)s * H + c] + eh);
            atomicAdd(&agg[(size_t)d * H + c], msg);
        }
    }
}

// ---------------- finalize: divide sums by counts ----------------
__global__ void k_finalize(const float* __restrict__ sc, const int* __restrict__ cc,
                           const float* __restrict__ st, const int* __restrict__ ct,
                           float* __restrict__ out) {
    int i = blockIdx.x * 256 + threadIdx.x;
    if (i < NG * H) {
        int g = i >> 7;
        out[i]          = sc[i] / fmaxf((float)cc[g], 1.f);
        out[NG * H + i] = st[i] / fmaxf((float)ct[g], 1.f);
    }
}

extern "C" void kernel_launch(void* const* d_in, const int* in_sizes, int n_in,
                              void* d_out, int out_size, void* d_ws, size_t ws_size,
                              hipStream_t stream) {
    (void)n_in; (void)out_size;
    const float* x           = (const float*)d_in[0];
    const float* node_weight = (const float*)d_in[1];
    const int*   edge_index  = (const int*)d_in[2];
    const float* edge_attr   = (const float*)d_in[3];
    const float* edge_weight = (const float*)d_in[4];
    const int*   batch       = (const int*)d_in[5];
    const int*   cnm         = (const int*)d_in[6];
    const int*   tnm         = (const int*)d_in[7];
    const int*   csub        = (const int*)d_in[8];
    const int*   sem         = (const int*)d_in[9];
    const void*  cmask       = d_in[10];

    const float* ctx_w_node = (const float*)d_in[11];
    const float* ctx_b_node = (const float*)d_in[12];
    const float* ctx_w_edge = (const float*)d_in[13];
    const float* ctx_b_edge = (const float*)d_in[14];
    const float* ctx_w_mp   = (const float*)d_in[15];
    const float* ctx_b_mp   = (const float*)d_in[16];
    const float* ctx_w_out  = (const float*)d_in[17];
    const float* ctx_b_out  = (const float*)d_in[18];
    const float* tgt_w_node = (const float*)d_in[19];
    const float* tgt_b_node = (const float*)d_in[20];
    const float* tgt_w_edge = (const float*)d_in[21];
    const float* tgt_b_edge = (const float*)d_in[22];
    const float* tgt_w_mp   = (const float*)d_in[23];
    const float* tgt_b_mp   = (const float*)d_in[24];
    const float* tgt_w_out  = (const float*)d_in[25];
    const float* tgt_b_out  = (const float*)d_in[26];

    const int N  = in_sizes[1];
    const int E  = in_sizes[4];
    const int NC = in_sizes[6];
    const int NT = in_sizes[7];
    const int ES = in_sizes[9];

    float* out = (float*)d_out;

    // workspace layout
    char* ws = (char*)d_ws;
    float* h_full = (float*)ws;  ws += (size_t)N  * H * sizeof(float);
    float* h_ctx  = (float*)ws;  ws += (size_t)NC * H * sizeof(float);
    float* agg    = (float*)ws;  ws += (size_t)N  * H * sizeof(float);
    float* sum_ctx = (float*)ws; ws += (size_t)NG * H * sizeof(float);
    float* sum_tgt = (float*)ws; ws += (size_t)NG * H * sizeof(float);
    int*   cnt_ctx = (int*)ws;   ws += (size_t)NG * sizeof(int);
    int*   cnt_tgt = (int*)ws;   ws += (size_t)NG * sizeof(int);
    int*   flag    = (int*)ws;   ws += sizeof(int);
    (void)ws_size;

    // zero pooled sums/counts/flag (contiguous region)
    size_t sums_bytes = (size_t)(2 * NG * H) * sizeof(float) + (size_t)(2 * NG) * sizeof(int) + sizeof(int);
    hipMemsetAsync(sum_ctx, 0, sums_bytes, stream);

    // sniff mask dtype
    int nwords = ES / 4; if (nwords > 8192) nwords = 8192;
    k_sniff<<<1, 256, 0, stream>>>((const unsigned int*)cmask, nwords, flag);

    const int MSG_GX = 8192;
    dim3 gN((N + 63) / 64, 2), gC((NC + 63) / 64, 2), gT((NT + 63) / 64, 2);

    // ---------- FULL graph pass (tgt params) ----------
    k_gemm_enc<false><<<gN, 256, 0, stream>>>(x, nullptr, N, tgt_w_node, tgt_b_node, h_full);
    for (int t = 0; t < 3; ++t) {
        hipMemsetAsync(agg, 0, (size_t)N * H * sizeof(float), stream);
        k_msg<0><<<MSG_GX, 256, 0, stream>>>(edge_index, edge_index + E, edge_weight,
                                             nullptr, nullptr, nullptr,
                                             edge_attr, tgt_w_edge, tgt_b_edge,
                                             h_full, agg, E);
        k_gemm_update<<<gN, 256, 0, stream>>>(agg, N, tgt_w_mp + t * H * H, tgt_b_mp + t * H, h_full);
    }
    k_gemm_pool<true><<<gT, 256, 0, stream>>>(h_full, tnm, batch, node_weight,
                                              tgt_w_out, tgt_b_out, sum_tgt, cnt_tgt, NT);

    // ---------- CTX subgraph pass (ctx params) ----------
    k_gemm_enc<true><<<gC, 256, 0, stream>>>(x, cnm, NC, ctx_w_node, ctx_b_node, h_ctx);
    for (int t = 0; t < 3; ++t) {
        hipMemsetAsync(agg, 0, (size_t)NC * H * sizeof(float), stream);
        k_msg<1><<<MSG_GX, 256, 0, stream>>>(csub, csub + ES, edge_weight,
                                             sem, cmask, flag,
                                             edge_attr, ctx_w_edge, ctx_b_edge,
                                             h_ctx, agg, ES);
        k_gemm_update<<<gC, 256, 0, stream>>>(agg, NC, ctx_w_mp + t * H * H, ctx_b_mp + t * H, h_ctx);
    }
    k_gemm_pool<false><<<gC, 256, 0, stream>>>(h_ctx, cnm, batch, node_weight,
                                               ctx_w_out, ctx_b_out, sum_ctx, cnt_ctx, NC);

    k_finalize<<<512, 256, 0, stream>>>(sum_ctx, cnt_ctx, sum_tgt, cnt_tgt, out);
}

// Round 3
// 2575.454 us; speedup vs baseline: 1.6152x; 1.1467x over previous
//
#include <hip/hip_runtime.h>
#include <stdint.h>

#define H 128
#define FN 133
#define FE 14
#define NG 1024
#define NCOPY 8

// ---------------- mask dtype sniff ----------------
// flag: 0 = int32 {0,1}, 1 = packed bytes, 2 = float32 {0.0,1.0}
__global__ void k_sniff(const unsigned int* __restrict__ w, int nwords, int* __restrict__ flag) {
    __shared__ int sawFloat, sawBig;
    if (threadIdx.x == 0) { sawFloat = 0; sawBig = 0; }
    __syncthreads();
    int f = 0, bg = 0;
    for (int i = threadIdx.x; i < nwords; i += blockDim.x) {
        unsigned int v = w[i];
        if (v == 0u || v == 1u) continue;
        if (v == 0x3F800000u) f = 1; else bg = 1;
    }
    if (f) atomicOr(&sawFloat, 1);
    if (bg) atomicOr(&sawBig, 1);
    __syncthreads();
    if (threadIdx.x == 0) *flag = sawBig ? 1 : (sawFloat ? 2 : 0);
}

__device__ __forceinline__ float mask_val(const void* mask, int mm, long e) {
    if (mm == 1)      return ((const unsigned char*)mask)[e] ? 1.f : 0.f;
    else if (mm == 2) return ((const float*)mask)[e];
    else              return ((const int*)mask)[e] ? 1.f : 0.f;
}

// =====================================================================
// Register-tiled fp32 GEMM family (unchanged from round 2)
// =====================================================================
template<bool GATHER>
__global__ __launch_bounds__(256)
void k_gemm_enc(const float* __restrict__ x, const int* __restrict__ map, int nrows,
                const float* __restrict__ w, const float* __restrict__ bias,
                float* __restrict__ hout) {
    __shared__ float w_lds[FN][64];
    __shared__ float a_lds[67][68];
    const int cbase = blockIdx.y * 64;
    for (int i = threadIdx.x; i < FN * 64; i += 256)
        w_lds[i >> 6][i & 63] = w[(i >> 6) * H + cbase + (i & 63)];
    const int tx = threadIdx.x & 15, ty = threadIdx.x >> 4;
    const int rbase = blockIdx.x * 64;
    float acc[4][4] = {};
    #pragma unroll
    for (int kc = 0; kc < 2; ++kc) {
        const int k0 = kc * 67;
        const int klen = kc ? 66 : 67;
        __syncthreads();
        for (int i = threadIdx.x; i < 64 * 67; i += 256) {
            int r = i / 67, kk = i % 67;
            int row = rbase + r;
            float v = 0.f;
            if (kk < klen && row < nrows) {
                int sr = GATHER ? map[row] : row;
                v = x[(size_t)sr * FN + k0 + kk];
            }
            a_lds[kk][r] = v;
        }
        __syncthreads();
        #pragma unroll 4
        for (int k = 0; k < klen; ++k) {
            float4 av = reinterpret_cast<const float4*>(&a_lds[k][0])[ty];
            float4 wv = reinterpret_cast<const float4*>(&w_lds[k0 + k][0])[tx];
            float aa[4] = {av.x, av.y, av.z, av.w};
            float ww[4] = {wv.x, wv.y, wv.z, wv.w};
            #pragma unroll
            for (int i2 = 0; i2 < 4; ++i2)
                #pragma unroll
                for (int j = 0; j < 4; ++j)
                    acc[i2][j] += aa[i2] * ww[j];
        }
    }
    float4 bv = reinterpret_cast<const float4*>(bias + cbase)[tx];
    float bb[4] = {bv.x, bv.y, bv.z, bv.w};
    #pragma unroll
    for (int i2 = 0; i2 < 4; ++i2) {
        int row = rbase + ty * 4 + i2;
        if (row < nrows) {
            float4 o;
            o.x = fmaxf(acc[i2][0] + bb[0], 0.f);
            o.y = fmaxf(acc[i2][1] + bb[1], 0.f);
            o.z = fmaxf(acc[i2][2] + bb[2], 0.f);
            o.w = fmaxf(acc[i2][3] + bb[3], 0.f);
            *reinterpret_cast<float4*>(hout + (size_t)row * H + cbase + tx * 4) = o;
        }
    }
}

__global__ __launch_bounds__(256)
void k_gemm_update(const float* __restrict__ agg, int nrows,
                   const float* __restrict__ w, const float* __restrict__ bias,
                   float* __restrict__ h) {
    __shared__ float w_lds[H][64];
    __shared__ float a_lds[64][68];
    const int cbase = blockIdx.y * 64;
    for (int i = threadIdx.x; i < H * 64; i += 256)
        w_lds[i >> 6][i & 63] = w[(i >> 6) * H + cbase + (i & 63)];
    const int tx = threadIdx.x & 15, ty = threadIdx.x >> 4;
    const int rbase = blockIdx.x * 64;
    const bool full = (rbase + 64 <= nrows);
    float acc[4][4] = {};
    #pragma unroll
    for (int kc = 0; kc < 2; ++kc) {
        const int k0 = kc * 64;
        __syncthreads();
        for (int i = threadIdx.x; i < 1024; i += 256) {
            int r = i >> 4, f = i & 15;
            int row = rbase + r;
            float4 v = make_float4(0.f, 0.f, 0.f, 0.f);
            if (full || row < nrows)
                v = reinterpret_cast<const float4*>(agg + (size_t)row * H + k0)[f];
            a_lds[f * 4 + 0][r] = v.x;
            a_lds[f * 4 + 1][r] = v.y;
            a_lds[f * 4 + 2][r] = v.z;
            a_lds[f * 4 + 3][r] = v.w;
        }
        __syncthreads();
        #pragma unroll 8
        for (int k = 0; k < 64; ++k) {
            float4 av = reinterpret_cast<const float4*>(&a_lds[k][0])[ty];
            float4 wv = reinterpret_cast<const float4*>(&w_lds[k0 + k][0])[tx];
            float aa[4] = {av.x, av.y, av.z, av.w};
            float ww[4] = {wv.x, wv.y, wv.z, wv.w};
            #pragma unroll
            for (int i2 = 0; i2 < 4; ++i2)
                #pragma unroll
                for (int j = 0; j < 4; ++j)
                    acc[i2][j] += aa[i2] * ww[j];
        }
    }
    float4 bv = reinterpret_cast<const float4*>(bias + cbase)[tx];
    float bb[4] = {bv.x, bv.y, bv.z, bv.w};
    #pragma unroll
    for (int i2 = 0; i2 < 4; ++i2) {
        int row = rbase + ty * 4 + i2;
        if (row < nrows) {
            size_t base = (size_t)row * H + cbase + tx * 4;
            float4 hv = *reinterpret_cast<const float4*>(h + base);
            float4 o;
            o.x = fmaxf(hv.x + acc[i2][0] + bb[0], 0.f);
            o.y = fmaxf(hv.y + acc[i2][1] + bb[1], 0.f);
            o.z = fmaxf(hv.z + acc[i2][2] + bb[2], 0.f);
            o.w = fmaxf(hv.w + acc[i2][3] + bb[3], 0.f);
            *reinterpret_cast<float4*>(h + base) = o;
        }
    }
}

// =====================================================================
// CSR build: histogram -> 2-level exclusive scan -> scatter
// =====================================================================
template<int MODE>
__global__ __launch_bounds__(256)
void k_hist(const int* __restrict__ dst, const float* __restrict__ edge_weight,
            const int* __restrict__ emap, const void* __restrict__ mask,
            const int* __restrict__ mmode_p, int* __restrict__ deg, int nedges) {
    int e = blockIdx.x * 256 + threadIdx.x;
    if (e >= nedges) return;
    int eo = MODE ? emap[e] : e;
    float w = edge_weight[eo];
    if (MODE) w *= mask_val(mask, *mmode_p, e);
    if (w != 0.f) atomicAdd(&deg[dst[e]], 1);
}

__global__ __launch_bounds__(256)
void k_scan1(const int* __restrict__ deg, int* __restrict__ off, int* __restrict__ bsum, int n) {
    __shared__ int tsum[256];
    const int tid = threadIdx.x;
    const int base = blockIdx.x * 1024;
    int local[4]; int s = 0;
    #pragma unroll
    for (int j = 0; j < 4; ++j) {
        int i = base + tid * 4 + j;
        local[j] = (i < n) ? deg[i] : 0;
        s += local[j];
    }
    tsum[tid] = s;
    __syncthreads();
    for (int d = 1; d < 256; d <<= 1) {
        int v = (tid >= d) ? tsum[tid - d] : 0;
        __syncthreads();
        tsum[tid] += v;
        __syncthreads();
    }
    int excl = tsum[tid] - s;
    #pragma unroll
    for (int j = 0; j < 4; ++j) {
        int i = base + tid * 4 + j;
        if (i < n) off[i] = excl;
        excl += local[j];
    }
    if (tid == 255) bsum[blockIdx.x] = tsum[255];
}

__global__ __launch_bounds__(256)
void k_scan2(int* __restrict__ bsum, int nb) {
    __shared__ int tsum[256];
    const int tid = threadIdx.x;
    int local[4]; int s = 0;
    #pragma unroll
    for (int j = 0; j < 4; ++j) {
        int i = tid * 4 + j;
        local[j] = (i < nb) ? bsum[i] : 0;
        s += local[j];
    }
    tsum[tid] = s;
    __syncthreads();
    for (int d = 1; d < 256; d <<= 1) {
        int v = (tid >= d) ? tsum[tid - d] : 0;
        __syncthreads();
        tsum[tid] += v;
        __syncthreads();
    }
    int excl = tsum[tid] - s;
    #pragma unroll
    for (int j = 0; j < 4; ++j) {
        int i = tid * 4 + j;
        if (i < nb) bsum[i] = excl;
        excl += local[j];
    }
}

__global__ __launch_bounds__(256)
void k_scan3(const int* __restrict__ bsum, int* __restrict__ off, int* __restrict__ cur, int n) {
    int i = blockIdx.x * 256 + threadIdx.x;
    if (i < n) {
        int o = off[i] + bsum[i >> 10];
        off[i] = o;
        cur[i] = o;
    }
}

template<int MODE>
__global__ __launch_bounds__(256)
void k_scatter(const int* __restrict__ src, const int* __restrict__ dst,
               const float* __restrict__ edge_weight,
               const int* __restrict__ emap, const void* __restrict__ mask,
               const int* __restrict__ mmode_p, int* __restrict__ cur,
               int* __restrict__ esrc, float* __restrict__ eew, int* __restrict__ eeo,
               int nedges) {
    int e = blockIdx.x * 256 + threadIdx.x;
    if (e >= nedges) return;
    int eo = MODE ? emap[e] : e;
    float w = edge_weight[eo];
    if (MODE) w *= mask_val(mask, *mmode_p, e);
    if (w != 0.f) {
        int pos = atomicAdd(&cur[dst[e]], 1);
        esrc[pos] = src[e];
        eew[pos]  = w;
        eeo[pos]  = eo;
    }
}

// =====================================================================
// CSR message pass: half-wave (32 lanes, float4) per node, no atomics.
// agg[v] = sum_{e in csr[v]} ew * (h[src] + relu(ea@we + be)); zero-deg -> 0
// =====================================================================
__global__ __launch_bounds__(256)
void k_msg_csr(const int* __restrict__ off, const int* __restrict__ deg,
               const int* __restrict__ esrc, const float* __restrict__ eew,
               const int* __restrict__ eeo,
               const float* __restrict__ edge_attr,
               const float* __restrict__ w_edge, const float* __restrict__ b_edge,
               const float* __restrict__ h, float* __restrict__ agg, int nnodes) {
    __shared__ float we_lds[FE * H];
    __shared__ float be_lds[H];
    for (int i = threadIdx.x; i < FE * H; i += 256) we_lds[i] = w_edge[i];
    if (threadIdx.x < H) be_lds[threadIdx.x] = b_edge[threadIdx.x];
    __syncthreads();
    const int lane = threadIdx.x & 63;
    const int wid  = threadIdx.x >> 6;
    const int sub  = lane >> 5;
    const int c    = (lane & 31) * 4;
    int v = blockIdx.x * 8 + wid * 2 + sub;
    if (v >= nnodes) return;
    float4 acc = make_float4(0.f, 0.f, 0.f, 0.f);
    const int o = off[v], d = deg[v];
    const float4 bev = *reinterpret_cast<const float4*>(be_lds + c);
    for (int j = o; j < o + d; ++j) {
        int s   = esrc[j];
        float w = eew[j];
        int eo  = eeo[j];
        const float* ea = edge_attr + (size_t)eo * FE;
        float4 hv = *reinterpret_cast<const float4*>(h + (size_t)s * H + c);
        float4 eh = bev;
        #pragma unroll
        for (int k = 0; k < FE; ++k) {
            float a = ea[k];
            const float* wr = we_lds + k * H + c;
            eh.x += a * wr[0]; eh.y += a * wr[1]; eh.z += a * wr[2]; eh.w += a * wr[3];
        }
        eh.x = fmaxf(eh.x, 0.f); eh.y = fmaxf(eh.y, 0.f);
        eh.z = fmaxf(eh.z, 0.f); eh.w = fmaxf(eh.w, 0.f);
        acc.x += w * (hv.x + eh.x); acc.y += w * (hv.y + eh.y);
        acc.z += w * (hv.z + eh.z); acc.w += w * (hv.w + eh.w);
    }
    *reinterpret_cast<float4*>(agg + (size_t)v * H + c) = acc;
}

// =====================================================================
// Pool stage 1: privatized weighted segment-sum of h rows (pre-GEMM).
// =====================================================================
template<bool GATHER>
__global__ __launch_bounds__(256)
void k_pool_sum(const float* __restrict__ h, const int* __restrict__ rowmap,
                const int* __restrict__ batch, const float* __restrict__ nodew,
                float* __restrict__ sbuf, float* __restrict__ cbuf, float* __restrict__ nbuf,
                int nrows) {
    int idx = blockIdx.x * 256 + threadIdx.x;
    int r = idx >> 5, q = idx & 31;
    if (r >= nrows) return;
    int oid = rowmap[r];
    int g = batch[oid];
    float nw = nodew[oid];
    int hr = GATHER ? oid : r;
    float4 v = *reinterpret_cast<const float4*>(h + (size_t)hr * H + q * 4);
    int copy = blockIdx.x & (NCOPY - 1);
    float* sp = sbuf + ((size_t)copy * NG + g) * H + q * 4;
    atomicAdd(sp + 0, nw * v.x);
    atomicAdd(sp + 1, nw * v.y);
    atomicAdd(sp + 2, nw * v.z);
    atomicAdd(sp + 3, nw * v.w);
    if (q == 0) {
        atomicAdd(cbuf + copy * NG + g, nw);
        atomicAdd(nbuf + copy * NG + g, 1.f);
    }
}

// Pool stage 2: out[g] = (s_g @ w_out + b_out * c_g) / max(n_g, 1)
__global__ __launch_bounds__(256)
void k_pool_gemm(const float* __restrict__ sbuf, const float* __restrict__ cbuf,
                 const float* __restrict__ nbuf,
                 const float* __restrict__ w, const float* __restrict__ bias,
                 float* __restrict__ outp) {
    __shared__ float s_lds[2][H];
    const int gbase = blockIdx.x * 2;
    for (int i = threadIdx.x; i < 2 * H; i += 256) {
        int gl = i >> 7, k = i & 127;
        float s = 0.f;
        for (int cp = 0; cp < NCOPY; ++cp)
            s += sbuf[((size_t)cp * NG + gbase + gl) * H + k];
        s_lds[gl][k] = s;
    }
    __syncthreads();
    const int gl = threadIdx.x >> 7, cc = threadIdx.x & 127;
    const int g = gbase + gl;
    float cg = 0.f, ng = 0.f;
    for (int cp = 0; cp < NCOPY; ++cp) {
        cg += cbuf[cp * NG + g];
        ng += nbuf[cp * NG + g];
    }
    float acc = bias[cc] * cg;
    #pragma unroll 8
    for (int k = 0; k < H; ++k) acc += s_lds[gl][k] * w[k * H + cc];
    outp[(size_t)g * H + cc] = acc / fmaxf(ng, 1.f);
}

extern "C" void kernel_launch(void* const* d_in, const int* in_sizes, int n_in,
                              void* d_out, int out_size, void* d_ws, size_t ws_size,
                              hipStream_t stream) {
    (void)n_in; (void)out_size; (void)ws_size;
    const float* x           = (const float*)d_in[0];
    const float* node_weight = (const float*)d_in[1];
    const int*   edge_index  = (const int*)d_in[2];
    const float* edge_attr   = (const float*)d_in[3];
    const float* edge_weight = (const float*)d_in[4];
    const int*   batch       = (const int*)d_in[5];
    const int*   cnm         = (const int*)d_in[6];
    const int*   tnm         = (const int*)d_in[7];
    const int*   csub        = (const int*)d_in[8];
    const int*   sem         = (const int*)d_in[9];
    const void*  cmask       = d_in[10];

    const float* ctx_w_node = (const float*)d_in[11];
    const float* ctx_b_node = (const float*)d_in[12];
    const float* ctx_w_edge = (const float*)d_in[13];
    const float* ctx_b_edge = (const float*)d_in[14];
    const float* ctx_w_mp   = (const float*)d_in[15];
    const float* ctx_b_mp   = (const float*)d_in[16];
    const float* ctx_w_out  = (const float*)d_in[17];
    const float* ctx_b_out  = (const float*)d_in[18];
    const float* tgt_w_node = (const float*)d_in[19];
    const float* tgt_b_node = (const float*)d_in[20];
    const float* tgt_w_edge = (const float*)d_in[21];
    const float* tgt_b_edge = (const float*)d_in[22];
    const float* tgt_w_mp   = (const float*)d_in[23];
    const float* tgt_b_mp   = (const float*)d_in[24];
    const float* tgt_w_out  = (const float*)d_in[25];
    const float* tgt_b_out  = (const float*)d_in[26];

    const int N  = in_sizes[1];
    const int E  = in_sizes[4];
    const int NC = in_sizes[6];
    const int NT = in_sizes[7];
    const int ES = in_sizes[9];

    float* out = (float*)d_out;

    // ---------------- workspace layout ----------------
    char* ws = (char*)d_ws;
    float* h_full = (float*)ws;  ws += (size_t)N  * H * sizeof(float);
    float* h_ctx  = (float*)ws;  ws += (size_t)NC * H * sizeof(float);
    float* agg    = (float*)ws;  ws += (size_t)N  * H * sizeof(float);
    int*   deg    = (int*)ws;    ws += (size_t)N * sizeof(int);
    int*   off    = (int*)ws;    ws += (size_t)N * sizeof(int);
    int*   cur    = (int*)ws;    ws += (size_t)N * sizeof(int);
    int*   bsum   = (int*)ws;    ws += 1024 * sizeof(int);
    int*   esrc   = (int*)ws;    ws += (size_t)E * sizeof(int);
    float* eew    = (float*)ws;  ws += (size_t)E * sizeof(float);
    int*   eeo    = (int*)ws;    ws += (size_t)E * sizeof(int);
    // pool buffers (contiguous zero region)
    float* s_ctx  = (float*)ws;  ws += (size_t)NCOPY * NG * H * sizeof(float);
    float* s_tgt  = (float*)ws;  ws += (size_t)NCOPY * NG * H * sizeof(float);
    float* c_ctx  = (float*)ws;  ws += (size_t)NCOPY * NG * sizeof(float);
    float* c_tgt  = (float*)ws;  ws += (size_t)NCOPY * NG * sizeof(float);
    float* n_ctx  = (float*)ws;  ws += (size_t)NCOPY * NG * sizeof(float);
    float* n_tgt  = (float*)ws;  ws += (size_t)NCOPY * NG * sizeof(float);
    int*   flag   = (int*)ws;    ws += sizeof(int);

    size_t zero_bytes = (size_t)(2 * NCOPY * NG * H + 4 * NCOPY * NG) * sizeof(float) + sizeof(int);
    hipMemsetAsync(s_ctx, 0, zero_bytes, stream);

    int nwords = ES / 4; if (nwords > 8192) nwords = 8192;
    k_sniff<<<1, 256, 0, stream>>>((const unsigned int*)cmask, nwords, flag);

    dim3 gN((N + 63) / 64, 2), gC((NC + 63) / 64, 2);

    // ================= FULL graph pass (tgt params) =================
    {
        const int* fsrc = edge_index;
        const int* fdst = edge_index + E;
        hipMemsetAsync(deg, 0, (size_t)N * sizeof(int), stream);
        int egrid = (E + 255) / 256;
        k_hist<0><<<egrid, 256, 0, stream>>>(fdst, edge_weight, nullptr, nullptr, nullptr, deg, E);
        int nb1 = (N + 1023) / 1024;
        k_scan1<<<nb1, 256, 0, stream>>>(deg, off, bsum, N);
        k_scan2<<<1, 256, 0, stream>>>(bsum, nb1);
        k_scan3<<<(N + 255) / 256, 256, 0, stream>>>(bsum, off, cur, N);
        k_scatter<0><<<egrid, 256, 0, stream>>>(fsrc, fdst, edge_weight, nullptr, nullptr, nullptr,
                                                cur, esrc, eew, eeo, E);
        k_gemm_enc<false><<<gN, 256, 0, stream>>>(x, nullptr, N, tgt_w_node, tgt_b_node, h_full);
        int mgrid = (N + 7) / 8;
        for (int t = 0; t < 3; ++t) {
            k_msg_csr<<<mgrid, 256, 0, stream>>>(off, deg, esrc, eew, eeo, edge_attr,
                                                 tgt_w_edge, tgt_b_edge, h_full, agg, N);
            k_gemm_update<<<gN, 256, 0, stream>>>(agg, N, tgt_w_mp + t * H * H, tgt_b_mp + t * H, h_full);
        }
        k_pool_sum<true><<<(NT * 32 + 255) / 256, 256, 0, stream>>>(h_full, tnm, batch, node_weight,
                                                                    s_tgt, c_tgt, n_tgt, NT);
        k_pool_gemm<<<NG / 2, 256, 0, stream>>>(s_tgt, c_tgt, n_tgt, tgt_w_out, tgt_b_out, out + (size_t)NG * H);
    }

    // ================= CTX subgraph pass (ctx params) =================
    {
        const int* csrc = csub;
        const int* cdst = csub + ES;
        hipMemsetAsync(deg, 0, (size_t)NC * sizeof(int), stream);
        int egrid = (ES + 255) / 256;
        k_hist<1><<<egrid, 256, 0, stream>>>(cdst, edge_weight, sem, cmask, flag, deg, ES);
        int nb1 = (NC + 1023) / 1024;
        k_scan1<<<nb1, 256, 0, stream>>>(deg, off, bsum, NC);
        k_scan2<<<1, 256, 0, stream>>>(bsum, nb1);
        k_scan3<<<(NC + 255) / 256, 256, 0, stream>>>(bsum, off, cur, NC);
        k_scatter<1><<<egrid, 256, 0, stream>>>(csrc, cdst, edge_weight, sem, cmask, flag,
                                                cur, esrc, eew, eeo, ES);
        k_gemm_enc<true><<<gC, 256, 0, stream>>>(x, cnm, NC, ctx_w_node, ctx_b_node, h_ctx);
        int mgrid = (NC + 7) / 8;
        for (int t = 0; t < 3; ++t) {
            k_msg_csr<<<mgrid, 256, 0, stream>>>(off, deg, esrc, eew, eeo, edge_attr,
                                                 ctx_w_edge, ctx_b_edge, h_ctx, agg, NC);
            k_gemm_update<<<gC, 256, 0, stream>>>(agg, NC, ctx_w_mp + t * H * H, ctx_b_mp + t * H, h_ctx);
        }
        k_pool_sum<false><<<(NC * 32 + 255) / 256, 256, 0, stream>>>(h_ctx, cnm, batch, node_weight,
                                                                     s_ctx, c_ctx, n_ctx, NC);
        k_pool_gemm<<<NG / 2, 256, 0, stream>>>(s_ctx, c_ctx, n_ctx, ctx_w_out, ctx_b_out, out);
    }
}

// Round 4
// 1998.018 us; speedup vs baseline: 2.0820x; 1.2890x over previous
//
#include <hip/hip_runtime.h>
#include <stdint.h>

#define H 128
#define FN 133
#define FE 14
#define NG 1024
#define APAD 132

// ---------------- mask dtype sniff ----------------
// flag: 0 = int32 {0,1}, 1 = packed bytes, 2 = float32 {0.0,1.0}
__global__ void k_sniff(const unsigned int* __restrict__ w, int nwords, int* __restrict__ flag) {
    __shared__ int sawFloat, sawBig;
    if (threadIdx.x == 0) { sawFloat = 0; sawBig = 0; }
    __syncthreads();
    int f = 0, bg = 0;
    for (int i = threadIdx.x; i < nwords; i += blockDim.x) {
        unsigned int v = w[i];
        if (v == 0u || v == 1u) continue;
        if (v == 0x3F800000u) f = 1; else bg = 1;
    }
    if (f) atomicOr(&sawFloat, 1);
    if (bg) atomicOr(&sawBig, 1);
    __syncthreads();
    if (threadIdx.x == 0) *flag = sawBig ? 1 : (sawFloat ? 2 : 0);
}

__device__ __forceinline__ float mask_val(const void* mask, int mm, long e) {
    if (mm == 1)      return ((const unsigned char*)mask)[e] ? 1.f : 0.f;
    else if (mm == 2) return ((const float*)mask)[e];
    else              return ((const int*)mask)[e] ? 1.f : 0.f;
}

// =====================================================================
// 8x8 register-tiled fp32 GEMMs: 256 threads -> 128x128 block tile,
// K chunked by 32. 4 ds_read_b128 per 64 FMA -> VALU-bound (~0.5 B/FLOP).
// =====================================================================

// ---------------- node encoder: h = relu(x[map?] @ w + b), K = 133 (5 zero-padded chunks) ----------------
template<bool GATHER>
__global__ __launch_bounds__(256)
void k_gemm_enc(const float* __restrict__ x, const int* __restrict__ map, int nrows,
                const float* __restrict__ w, const float* __restrict__ bias,
                float* __restrict__ hout) {
    __shared__ float w_lds[32][H];
    __shared__ float a_lds[32][APAD];
    __shared__ int   m_lds[128];
    const int tid = threadIdx.x;
    const int rbase = blockIdx.x * 128;
    if (GATHER && tid < 128) {
        int row = rbase + tid;
        m_lds[tid] = (row < nrows) ? map[row] : 0;
    }
    const int tx = tid & 15, ty = tid >> 4;
    float acc[8][8] = {};
    for (int kc = 0; kc < 5; ++kc) {
        const int k0 = kc * 32;
        __syncthreads();
        for (int i = tid; i < 32 * 32; i += 256) {
            int kk = i >> 5, c4 = i & 31;
            float4 v = make_float4(0.f, 0.f, 0.f, 0.f);
            if (k0 + kk < FN)
                v = reinterpret_cast<const float4*>(w + (size_t)(k0 + kk) * H)[c4];
            *reinterpret_cast<float4*>(&w_lds[kk][c4 * 4]) = v;
        }
        for (int i = tid; i < 128 * 32; i += 256) {
            int r = i >> 5, kk = i & 31;
            int row = rbase + r;
            float v = 0.f;
            if (row < nrows && k0 + kk < FN) {
                int sr = GATHER ? m_lds[r] : row;
                v = x[(size_t)sr * FN + k0 + kk];
            }
            a_lds[kk][r] = v;
        }
        __syncthreads();
        #pragma unroll 4
        for (int k = 0; k < 32; ++k) {
            float4 a0 = *reinterpret_cast<const float4*>(&a_lds[k][ty * 8]);
            float4 a1 = *reinterpret_cast<const float4*>(&a_lds[k][ty * 8 + 4]);
            float4 w0 = *reinterpret_cast<const float4*>(&w_lds[k][tx * 8]);
            float4 w1 = *reinterpret_cast<const float4*>(&w_lds[k][tx * 8 + 4]);
            float aa[8] = {a0.x, a0.y, a0.z, a0.w, a1.x, a1.y, a1.z, a1.w};
            float ww[8] = {w0.x, w0.y, w0.z, w0.w, w1.x, w1.y, w1.z, w1.w};
            #pragma unroll
            for (int i2 = 0; i2 < 8; ++i2)
                #pragma unroll
                for (int j = 0; j < 8; ++j)
                    acc[i2][j] += aa[i2] * ww[j];
        }
    }
    float4 b0 = reinterpret_cast<const float4*>(bias)[tx * 2];
    float4 b1 = reinterpret_cast<const float4*>(bias)[tx * 2 + 1];
    float bb[8] = {b0.x, b0.y, b0.z, b0.w, b1.x, b1.y, b1.z, b1.w};
    #pragma unroll
    for (int i2 = 0; i2 < 8; ++i2) {
        int row = rbase + ty * 8 + i2;
        if (row < nrows) {
            float4 o0, o1;
            o0.x = fmaxf(acc[i2][0] + bb[0], 0.f); o0.y = fmaxf(acc[i2][1] + bb[1], 0.f);
            o0.z = fmaxf(acc[i2][2] + bb[2], 0.f); o0.w = fmaxf(acc[i2][3] + bb[3], 0.f);
            o1.x = fmaxf(acc[i2][4] + bb[4], 0.f); o1.y = fmaxf(acc[i2][5] + bb[5], 0.f);
            o1.z = fmaxf(acc[i2][6] + bb[6], 0.f); o1.w = fmaxf(acc[i2][7] + bb[7], 0.f);
            float* hp = hout + (size_t)row * H + tx * 8;
            *reinterpret_cast<float4*>(hp)     = o0;
            *reinterpret_cast<float4*>(hp + 4) = o1;
        }
    }
}

// ---------------- h = relu(h + agg @ w_mp + b_mp), K = 128, in place ----------------
__global__ __launch_bounds__(256)
void k_gemm_update(const float* __restrict__ agg, int nrows,
                   const float* __restrict__ w, const float* __restrict__ bias,
                   float* __restrict__ h) {
    __shared__ float w_lds[32][H];
    __shared__ float a_lds[32][APAD];
    const int tid = threadIdx.x;
    const int rbase = blockIdx.x * 128;
    const int tx = tid & 15, ty = tid >> 4;
    float acc[8][8] = {};
    for (int kc = 0; kc < 4; ++kc) {
        const int k0 = kc * 32;
        __syncthreads();
        for (int i = tid; i < 32 * 32; i += 256) {
            int kk = i >> 5, c4 = i & 31;
            float4 v = reinterpret_cast<const float4*>(w + (size_t)(k0 + kk) * H)[c4];
            *reinterpret_cast<float4*>(&w_lds[kk][c4 * 4]) = v;
        }
        for (int i = tid; i < 128 * 8; i += 256) {
            int r = i >> 3, f = i & 7;
            int row = rbase + r;
            float4 v = make_float4(0.f, 0.f, 0.f, 0.f);
            if (row < nrows)
                v = reinterpret_cast<const float4*>(agg + (size_t)row * H + k0)[f];
            a_lds[f * 4 + 0][r] = v.x;
            a_lds[f * 4 + 1][r] = v.y;
            a_lds[f * 4 + 2][r] = v.z;
            a_lds[f * 4 + 3][r] = v.w;
        }
        __syncthreads();
        #pragma unroll 4
        for (int k = 0; k < 32; ++k) {
            float4 a0 = *reinterpret_cast<const float4*>(&a_lds[k][ty * 8]);
            float4 a1 = *reinterpret_cast<const float4*>(&a_lds[k][ty * 8 + 4]);
            float4 w0 = *reinterpret_cast<const float4*>(&w_lds[k][tx * 8]);
            float4 w1 = *reinterpret_cast<const float4*>(&w_lds[k][tx * 8 + 4]);
            float aa[8] = {a0.x, a0.y, a0.z, a0.w, a1.x, a1.y, a1.z, a1.w};
            float ww[8] = {w0.x, w0.y, w0.z, w0.w, w1.x, w1.y, w1.z, w1.w};
            #pragma unroll
            for (int i2 = 0; i2 < 8; ++i2)
                #pragma unroll
                for (int j = 0; j < 8; ++j)
                    acc[i2][j] += aa[i2] * ww[j];
        }
    }
    float4 b0 = reinterpret_cast<const float4*>(bias)[tx * 2];
    float4 b1 = reinterpret_cast<const float4*>(bias)[tx * 2 + 1];
    float bb[8] = {b0.x, b0.y, b0.z, b0.w, b1.x, b1.y, b1.z, b1.w};
    #pragma unroll
    for (int i2 = 0; i2 < 8; ++i2) {
        int row = rbase + ty * 8 + i2;
        if (row < nrows) {
            float* hp = h + (size_t)row * H + tx * 8;
            float4 h0 = *reinterpret_cast<const float4*>(hp);
            float4 h1 = *reinterpret_cast<const float4*>(hp + 4);
            float4 o0, o1;
            o0.x = fmaxf(h0.x + acc[i2][0] + bb[0], 0.f); o0.y = fmaxf(h0.y + acc[i2][1] + bb[1], 0.f);
            o0.z = fmaxf(h0.z + acc[i2][2] + bb[2], 0.f); o0.w = fmaxf(h0.w + acc[i2][3] + bb[3], 0.f);
            o1.x = fmaxf(h1.x + acc[i2][4] + bb[4], 0.f); o1.y = fmaxf(h1.y + acc[i2][5] + bb[5], 0.f);
            o1.z = fmaxf(h1.z + acc[i2][6] + bb[6], 0.f); o1.w = fmaxf(h1.w + acc[i2][7] + bb[7], 0.f);
            *reinterpret_cast<float4*>(hp)     = o0;
            *reinterpret_cast<float4*>(hp + 4) = o1;
        }
    }
}

// =====================================================================
// Edge CSR build: histogram -> 2-level exclusive scan -> scatter
// =====================================================================
template<int MODE>
__global__ __launch_bounds__(256)
void k_hist(const int* __restrict__ dst, const float* __restrict__ edge_weight,
            const int* __restrict__ emap, const void* __restrict__ mask,
            const int* __restrict__ mmode_p, int* __restrict__ deg, int nedges) {
    int e = blockIdx.x * 256 + threadIdx.x;
    if (e >= nedges) return;
    int eo = MODE ? emap[e] : e;
    float w = edge_weight[eo];
    if (MODE) w *= mask_val(mask, *mmode_p, e);
    if (w != 0.f) atomicAdd(&deg[dst[e]], 1);
}

__global__ __launch_bounds__(256)
void k_scan1(const int* __restrict__ deg, int* __restrict__ off, int* __restrict__ bsum, int n) {
    __shared__ int tsum[256];
    const int tid = threadIdx.x;
    const int base = blockIdx.x * 1024;
    int local[4]; int s = 0;
    #pragma unroll
    for (int j = 0; j < 4; ++j) {
        int i = base + tid * 4 + j;
        local[j] = (i < n) ? deg[i] : 0;
        s += local[j];
    }
    tsum[tid] = s;
    __syncthreads();
    for (int d = 1; d < 256; d <<= 1) {
        int v = (tid >= d) ? tsum[tid - d] : 0;
        __syncthreads();
        tsum[tid] += v;
        __syncthreads();
    }
    int excl = tsum[tid] - s;
    #pragma unroll
    for (int j = 0; j < 4; ++j) {
        int i = base + tid * 4 + j;
        if (i < n) off[i] = excl;
        excl += local[j];
    }
    if (tid == 255) bsum[blockIdx.x] = tsum[255];
}

__global__ __launch_bounds__(256)
void k_scan2(int* __restrict__ bsum, int nb) {
    __shared__ int tsum[256];
    const int tid = threadIdx.x;
    int local[4]; int s = 0;
    #pragma unroll
    for (int j = 0; j < 4; ++j) {
        int i = tid * 4 + j;
        local[j] = (i < nb) ? bsum[i] : 0;
        s += local[j];
    }
    tsum[tid] = s;
    __syncthreads();
    for (int d = 1; d < 256; d <<= 1) {
        int v = (tid >= d) ? tsum[tid - d] : 0;
        __syncthreads();
        tsum[tid] += v;
        __syncthreads();
    }
    int excl = tsum[tid] - s;
    #pragma unroll
    for (int j = 0; j < 4; ++j) {
        int i = tid * 4 + j;
        if (i < nb) bsum[i] = excl;
        excl += local[j];
    }
}

__global__ __launch_bounds__(256)
void k_scan3(const int* __restrict__ bsum, int* __restrict__ off, int* __restrict__ cur, int n) {
    int i = blockIdx.x * 256 + threadIdx.x;
    if (i < n) {
        int o = off[i] + bsum[i >> 10];
        off[i] = o;
        cur[i] = o;
    }
}

template<int MODE>
__global__ __launch_bounds__(256)
void k_scatter(const int* __restrict__ src, const int* __restrict__ dst,
               const float* __restrict__ edge_weight,
               const int* __restrict__ emap, const void* __restrict__ mask,
               const int* __restrict__ mmode_p, int* __restrict__ cur,
               int* __restrict__ esrc, float* __restrict__ eew, int* __restrict__ eeo,
               int nedges) {
    int e = blockIdx.x * 256 + threadIdx.x;
    if (e >= nedges) return;
    int eo = MODE ? emap[e] : e;
    float w = edge_weight[eo];
    if (MODE) w *= mask_val(mask, *mmode_p, e);
    if (w != 0.f) {
        int pos = atomicAdd(&cur[dst[e]], 1);
        esrc[pos] = src[e];
        eew[pos]  = w;
        eeo[pos]  = eo;
    }
}

// =====================================================================
// CSR message pass: half-wave (32 lanes, float4) per node, no atomics.
// =====================================================================
__global__ __launch_bounds__(256)
void k_msg_csr(const int* __restrict__ off, const int* __restrict__ deg,
               const int* __restrict__ esrc, const float* __restrict__ eew,
               const int* __restrict__ eeo,
               const float* __restrict__ edge_attr,
               const float* __restrict__ w_edge, const float* __restrict__ b_edge,
               const float* __restrict__ h, float* __restrict__ agg, int nnodes) {
    __shared__ float we_lds[FE * H];
    __shared__ float be_lds[H];
    for (int i = threadIdx.x; i < FE * H; i += 256) we_lds[i] = w_edge[i];
    if (threadIdx.x < H) be_lds[threadIdx.x] = b_edge[threadIdx.x];
    __syncthreads();
    const int lane = threadIdx.x & 63;
    const int wid  = threadIdx.x >> 6;
    const int sub  = lane >> 5;
    const int c    = (lane & 31) * 4;
    int v = blockIdx.x * 8 + wid * 2 + sub;
    if (v >= nnodes) return;
    float4 acc = make_float4(0.f, 0.f, 0.f, 0.f);
    const int o = off[v], d = deg[v];
    const float4 bev = *reinterpret_cast<const float4*>(be_lds + c);
    for (int j = o; j < o + d; ++j) {
        int s   = esrc[j];
        float w = eew[j];
        int eo  = eeo[j];
        const float* ea = edge_attr + (size_t)eo * FE;
        float4 hv = *reinterpret_cast<const float4*>(h + (size_t)s * H + c);
        float4 eh = bev;
        #pragma unroll
        for (int k = 0; k < FE; ++k) {
            float a = ea[k];
            const float* wr = we_lds + k * H + c;
            eh.x += a * wr[0]; eh.y += a * wr[1]; eh.z += a * wr[2]; eh.w += a * wr[3];
        }
        eh.x = fmaxf(eh.x, 0.f); eh.y = fmaxf(eh.y, 0.f);
        eh.z = fmaxf(eh.z, 0.f); eh.w = fmaxf(eh.w, 0.f);
        acc.x += w * (hv.x + eh.x); acc.y += w * (hv.y + eh.y);
        acc.z += w * (hv.z + eh.z); acc.w += w * (hv.w + eh.w);
    }
    *reinterpret_cast<float4*>(agg + (size_t)v * H + c) = acc;
}

// =====================================================================
// Group-CSR pool: no atomics on the fat path.
// =====================================================================
__global__ __launch_bounds__(256)
void k_ghist(const int* __restrict__ rowmap, const int* __restrict__ batch,
             int* __restrict__ deg_g, int nrows) {
    int r = blockIdx.x * 256 + threadIdx.x;
    if (r < nrows) atomicAdd(&deg_g[batch[rowmap[r]]], 1);
}

__global__ __launch_bounds__(256)
void k_gscan(const int* __restrict__ deg, int* __restrict__ off, int* __restrict__ cur) {
    __shared__ int tsum[256];
    const int tid = threadIdx.x;
    int local[4]; int s = 0;
    #pragma unroll
    for (int j = 0; j < 4; ++j) { local[j] = deg[tid * 4 + j]; s += local[j]; }
    tsum[tid] = s;
    __syncthreads();
    for (int d = 1; d < 256; d <<= 1) {
        int v = (tid >= d) ? tsum[tid - d] : 0;
        __syncthreads();
        tsum[tid] += v;
        __syncthreads();
    }
    int excl = tsum[tid] - s;
    #pragma unroll
    for (int j = 0; j < 4; ++j) {
        off[tid * 4 + j] = excl;
        cur[tid * 4 + j] = excl;
        excl += local[j];
    }
}

template<bool GATHER>
__global__ __launch_bounds__(256)
void k_gscatter(const int* __restrict__ rowmap, const int* __restrict__ batch,
                const float* __restrict__ nodew, int* __restrict__ cur,
                int* __restrict__ prow, float* __restrict__ pnw, int nrows) {
    int r = blockIdx.x * 256 + threadIdx.x;
    if (r >= nrows) return;
    int oid = rowmap[r];
    int g = batch[oid];
    int pos = atomicAdd(&cur[g], 1);
    prow[pos] = GATHER ? oid : r;
    pnw[pos]  = nodew[oid];
}

// One block per group: s = sum nw*h[row]; out = (s@W + b*sum(nw)) / max(cnt,1)
__global__ __launch_bounds__(256)
void k_pool(const int* __restrict__ off_g, const int* __restrict__ deg_g,
            const int* __restrict__ prow, const float* __restrict__ pnw,
            const float* __restrict__ h,
            const float* __restrict__ w, const float* __restrict__ bias,
            float* __restrict__ outp) {
    __shared__ float s_lds[4][H];
    __shared__ float ssum[H];
    __shared__ float r_lds[2][H];
    __shared__ float cg_lds[4];
    const int g = blockIdx.x;
    const int o = off_g[g], cnt = deg_g[g];
    const int wv = threadIdx.x >> 6, lane = threadIdx.x & 63;
    float ax = 0.f, ay = 0.f, cg = 0.f;
    for (int i = wv; i < cnt; i += 4) {
        int hrow = prow[o + i];
        float nw = pnw[o + i];
        float2 v = *reinterpret_cast<const float2*>(h + (size_t)hrow * H + lane * 2);
        ax += nw * v.x; ay += nw * v.y; cg += nw;
    }
    s_lds[wv][lane * 2]     = ax;
    s_lds[wv][lane * 2 + 1] = ay;
    if (lane == 0) cg_lds[wv] = cg;
    __syncthreads();
    if (threadIdx.x < H)
        ssum[threadIdx.x] = s_lds[0][threadIdx.x] + s_lds[1][threadIdx.x]
                          + s_lds[2][threadIdx.x] + s_lds[3][threadIdx.x];
    __syncthreads();
    const int c = threadIdx.x & 127, kh = threadIdx.x >> 7;
    float p = 0.f;
    #pragma unroll 8
    for (int k = 0; k < 64; ++k)
        p += ssum[kh * 64 + k] * w[(size_t)(kh * 64 + k) * H + c];
    r_lds[kh][c] = p;
    __syncthreads();
    if (threadIdx.x < H) {
        float cga = cg_lds[0] + cg_lds[1] + cg_lds[2] + cg_lds[3];
        float val = r_lds[0][c] + r_lds[1][c] + bias[c] * cga;
        outp[(size_t)g * H + c] = val / fmaxf((float)cnt, 1.f);
    }
}

extern "C" void kernel_launch(void* const* d_in, const int* in_sizes, int n_in,
                              void* d_out, int out_size, void* d_ws, size_t ws_size,
                              hipStream_t stream) {
    (void)n_in; (void)out_size; (void)ws_size;
    const float* x           = (const float*)d_in[0];
    const float* node_weight = (const float*)d_in[1];
    const int*   edge_index  = (const int*)d_in[2];
    const float* edge_attr   = (const float*)d_in[3];
    const float* edge_weight = (const float*)d_in[4];
    const int*   batch       = (const int*)d_in[5];
    const int*   cnm         = (const int*)d_in[6];
    const int*   tnm         = (const int*)d_in[7];
    const int*   csub        = (const int*)d_in[8];
    const int*   sem         = (const int*)d_in[9];
    const void*  cmask       = d_in[10];

    const float* ctx_w_node = (const float*)d_in[11];
    const float* ctx_b_node = (const float*)d_in[12];
    const float* ctx_w_edge = (const float*)d_in[13];
    const float* ctx_b_edge = (const float*)d_in[14];
    const float* ctx_w_mp   = (const float*)d_in[15];
    const float* ctx_b_mp   = (const float*)d_in[16];
    const float* ctx_w_out  = (const float*)d_in[17];
    const float* ctx_b_out  = (const float*)d_in[18];
    const float* tgt_w_node = (const float*)d_in[19];
    const float* tgt_b_node = (const float*)d_in[20];
    const float* tgt_w_edge = (const float*)d_in[21];
    const float* tgt_b_edge = (const float*)d_in[22];
    const float* tgt_w_mp   = (const float*)d_in[23];
    const float* tgt_b_mp   = (const float*)d_in[24];
    const float* tgt_w_out  = (const float*)d_in[25];
    const float* tgt_b_out  = (const float*)d_in[26];

    const int N  = in_sizes[1];
    const int E  = in_sizes[4];
    const int NC = in_sizes[6];
    const int NT = in_sizes[7];
    const int ES = in_sizes[9];
    const int NMAX = (NT > NC) ? NT : NC;

    float* out = (float*)d_out;

    // ---------------- workspace layout ----------------
    char* ws = (char*)d_ws;
    float* h_full = (float*)ws;  ws += (size_t)N  * H * sizeof(float);
    float* h_ctx  = (float*)ws;  ws += (size_t)NC * H * sizeof(float);
    float* agg    = (float*)ws;  ws += (size_t)N  * H * sizeof(float);
    int*   deg    = (int*)ws;    ws += (size_t)N * sizeof(int);
    int*   off    = (int*)ws;    ws += (size_t)N * sizeof(int);
    int*   cur    = (int*)ws;    ws += (size_t)N * sizeof(int);
    int*   bsum   = (int*)ws;    ws += 1024 * sizeof(int);
    int*   esrc   = (int*)ws;    ws += (size_t)E * sizeof(int);
    float* eew    = (float*)ws;  ws += (size_t)E * sizeof(float);
    int*   eeo    = (int*)ws;    ws += (size_t)E * sizeof(int);
    int*   deg_g  = (int*)ws;    ws += NG * sizeof(int);
    int*   off_g  = (int*)ws;    ws += NG * sizeof(int);
    int*   cur_g  = (int*)ws;    ws += NG * sizeof(int);
    int*   prow   = (int*)ws;    ws += (size_t)NMAX * sizeof(int);
    float* pnw    = (float*)ws;  ws += (size_t)NMAX * sizeof(float);
    int*   flag   = (int*)ws;    ws += sizeof(int);

    int nwords = ES / 4; if (nwords > 8192) nwords = 8192;
    k_sniff<<<1, 256, 0, stream>>>((const unsigned int*)cmask, nwords, flag);

    dim3 gN((N + 127) / 128), gC((NC + 127) / 128);

    // ================= FULL graph pass (tgt params) =================
    {
        const int* fsrc = edge_index;
        const int* fdst = edge_index + E;
        hipMemsetAsync(deg, 0, (size_t)N * sizeof(int), stream);
        int egrid = (E + 255) / 256;
        k_hist<0><<<egrid, 256, 0, stream>>>(fdst, edge_weight, nullptr, nullptr, nullptr, deg, E);
        int nb1 = (N + 1023) / 1024;
        k_scan1<<<nb1, 256, 0, stream>>>(deg, off, bsum, N);
        k_scan2<<<1, 256, 0, stream>>>(bsum, nb1);
        k_scan3<<<(N + 255) / 256, 256, 0, stream>>>(bsum, off, cur, N);
        k_scatter<0><<<egrid, 256, 0, stream>>>(fsrc, fdst, edge_weight, nullptr, nullptr, nullptr,
                                                cur, esrc, eew, eeo, E);
        k_gemm_enc<false><<<gN, 256, 0, stream>>>(x, nullptr, N, tgt_w_node, tgt_b_node, h_full);
        int mgrid = (N + 7) / 8;
        for (int t = 0; t < 3; ++t) {
            k_msg_csr<<<mgrid, 256, 0, stream>>>(off, deg, esrc, eew, eeo, edge_attr,
                                                 tgt_w_edge, tgt_b_edge, h_full, agg, N);
            k_gemm_update<<<gN, 256, 0, stream>>>(agg, N, tgt_w_mp + t * H * H, tgt_b_mp + t * H, h_full);
        }
        hipMemsetAsync(deg_g, 0, NG * sizeof(int), stream);
        k_ghist<<<(NT + 255) / 256, 256, 0, stream>>>(tnm, batch, deg_g, NT);
        k_gscan<<<1, 256, 0, stream>>>(deg_g, off_g, cur_g);
        k_gscatter<true><<<(NT + 255) / 256, 256, 0, stream>>>(tnm, batch, node_weight, cur_g, prow, pnw, NT);
        k_pool<<<NG, 256, 0, stream>>>(off_g, deg_g, prow, pnw, h_full, tgt_w_out, tgt_b_out,
                                       out + (size_t)NG * H);
    }

    // ================= CTX subgraph pass (ctx params) =================
    {
        const int* csrc = csub;
        const int* cdst = csub + ES;
        hipMemsetAsync(deg, 0, (size_t)NC * sizeof(int), stream);
        int egrid = (ES + 255) / 256;
        k_hist<1><<<egrid, 256, 0, stream>>>(cdst, edge_weight, sem, cmask, flag, deg, ES);
        int nb1 = (NC + 1023) / 1024;
        k_scan1<<<nb1, 256, 0, stream>>>(deg, off, bsum, NC);
        k_scan2<<<1, 256, 0, stream>>>(bsum, nb1);
        k_scan3<<<(NC + 255) / 256, 256, 0, stream>>>(bsum, off, cur, NC);
        k_scatter<1><<<egrid, 256, 0, stream>>>(csrc, cdst, edge_weight, sem, cmask, flag,
                                                cur, esrc, eew, eeo, ES);
        k_gemm_enc<true><<<gC, 256, 0, stream>>>(x, cnm, NC, ctx_w_node, ctx_b_node, h_ctx);
        int mgrid = (NC + 7) / 8;
        for (int t = 0; t < 3; ++t) {
            k_msg_csr<<<mgrid, 256, 0, stream>>>(off, deg, esrc, eew, eeo, edge_attr,
                                                 ctx_w_edge, ctx_b_edge, h_ctx, agg, NC);
            k_gemm_update<<<gC, 256, 0, stream>>>(agg, NC, ctx_w_mp + t * H * H, ctx_b_mp + t * H, h_ctx);
        }
        hipMemsetAsync(deg_g, 0, NG * sizeof(int), stream);
        k_ghist<<<(NC + 255) / 256, 256, 0, stream>>>(cnm, batch, deg_g, NC);
        k_gscan<<<1, 256, 0, stream>>>(deg_g, off_g, cur_g);
        k_gscatter<false><<<(NC + 255) / 256, 256, 0, stream>>>(cnm, batch, node_weight, cur_g, prow, pnw, NC);
        k_pool<<<NG, 256, 0, stream>>>(off_g, deg_g, prow, pnw, h_ctx, ctx_w_out, ctx_b_out, out);
    }
}